// Round 4
// baseline (7848.782 us; speedup 1.0000x reference)
//
#include <hip/hip_runtime.h>
#include <math.h>

#define Bz 64
#define Tz 32
#define Uz 512
#define NITER 31
#define G4 2048

typedef unsigned long long ull;

__device__ __forceinline__ float sigf(float x) { return 1.f / (1.f + expf(-x)); }

#define AT_LOADF(p)   __hip_atomic_load((p), __ATOMIC_RELAXED, __HIP_MEMORY_SCOPE_AGENT)
#define AT_LOADI(p)   __hip_atomic_load((p), __ATOMIC_RELAXED, __HIP_MEMORY_SCOPE_AGENT)
#define AT_LOAD64(p)  __hip_atomic_load((p), __ATOMIC_RELAXED, __HIP_MEMORY_SCOPE_AGENT)
#define AT_STORE(p,v) __hip_atomic_store((p), (v), __ATOMIC_RELAXED, __HIP_MEMORY_SCOPE_AGENT)

// poll 32 per-block flag lines; call with 32 active lanes (lane<32 of one wave)
__device__ __forceinline__ void poll32(unsigned* fl, unsigned target) {
  int sl = threadIdx.x & 63;
  unsigned v;
  do {
    v = __hip_atomic_fetch_add(&fl[sl * 16], 0u, __ATOMIC_RELAXED, __HIP_MEMORY_SCOPE_AGENT);
  } while (__any((int)(v < target)));
}

// ---------------- generic f32 GEMM: C[M,N] = A[rows][K] @ B[K,N] (+bias) ----------------
__global__ __launch_bounds__(256) void gemm_f32(
    const float* __restrict__ A, const int* __restrict__ Arows, int lda,
    const float* __restrict__ Bm, int ldb, const float* __restrict__ bias,
    float* __restrict__ C, int N, int K)
{
  __shared__ __align__(16) float As[16][68];
  __shared__ __align__(16) float Bs[16][68];
  const int tid = threadIdx.x;
  const int bm = blockIdx.y, bn = blockIdx.x;
  const int tx = tid & 15, ty = tid >> 4;
  float acc[4][4] = {{0.f}};
  const int sm = tid >> 2, sk = (tid & 3) * 4;
  const int arow = Arows ? Arows[bm * 64 + sm] : (bm * 64 + sm);
  const float* Ap = A + (size_t)arow * lda + sk;
  const int bk = tid >> 4, bn4 = (tid & 15) * 4;
  const float* Bp = Bm + (size_t)bk * ldb + bn * 64 + bn4;
  for (int kk = 0; kk < K; kk += 16) {
    float4 av = *(const float4*)(Ap + kk);
    float4 bv = *(const float4*)(Bp + (size_t)kk * ldb);
    As[sk + 0][sm] = av.x; As[sk + 1][sm] = av.y;
    As[sk + 2][sm] = av.z; As[sk + 3][sm] = av.w;
    *(float4*)&Bs[bk][bn4] = bv;
    __syncthreads();
#pragma unroll
    for (int kt = 0; kt < 16; ++kt) {
      float4 a = *(const float4*)&As[kt][ty * 4];
      float4 b = *(const float4*)&Bs[kt][tx * 4];
      acc[0][0] += a.x * b.x; acc[0][1] += a.x * b.y; acc[0][2] += a.x * b.z; acc[0][3] += a.x * b.w;
      acc[1][0] += a.y * b.x; acc[1][1] += a.y * b.y; acc[1][2] += a.y * b.z; acc[1][3] += a.y * b.w;
      acc[2][0] += a.z * b.x; acc[2][1] += a.z * b.y; acc[2][2] += a.z * b.z; acc[2][3] += a.z * b.w;
      acc[3][0] += a.w * b.x; acc[3][1] += a.w * b.y; acc[3][2] += a.w * b.z; acc[3][3] += a.w * b.w;
    }
    __syncthreads();
  }
  const int cm = bm * 64 + ty * 4, cn = bn * 64 + tx * 4;
  float bc0 = bias ? bias[cn + 0] : 0.f;
  float bc1 = bias ? bias[cn + 1] : 0.f;
  float bc2 = bias ? bias[cn + 2] : 0.f;
  float bc3 = bias ? bias[cn + 3] : 0.f;
#pragma unroll
  for (int i = 0; i < 4; ++i) {
    float4 o;
    o.x = acc[i][0] + bc0; o.y = acc[i][1] + bc1;
    o.z = acc[i][2] + bc2; o.w = acc[i][3] + bc3;
    *(float4*)&C[(size_t)(cm + i) * N + cn] = o;
  }
}

__global__ void init_kernel(unsigned* __restrict__ flags) {
  int i = blockIdx.x * blockDim.x + threadIdx.x;
  if (i < 8192) flags[i] = 0u;
}

// GEMM for one group: h from LDS (contiguous b128), W in regs, shuffle k-reduce.
#define DO_GEMM(HRED, GIDX, GV)                                                          \
  {                                                                                      \
    float4 a0 = {0,0,0,0}, a1 = {0,0,0,0}, a2 = {0,0,0,0}, a3 = {0,0,0,0};               \
    _Pragma("unroll")                                                                    \
    for (int kk = 0; kk < 16; ++kk) {                                                    \
      float4 hv = *(const float4*)&HRED[(kk * 32 + ks) * 4];                             \
      a0.x += hv.x * w4[kk].x; a0.y += hv.x * w4[kk].y;                                  \
      a0.z += hv.x * w4[kk].z; a0.w += hv.x * w4[kk].w;                                  \
      a1.x += hv.y * w4[kk].x; a1.y += hv.y * w4[kk].y;                                  \
      a1.z += hv.y * w4[kk].z; a1.w += hv.y * w4[kk].w;                                  \
      a2.x += hv.z * w4[kk].x; a2.y += hv.z * w4[kk].y;                                  \
      a2.z += hv.z * w4[kk].z; a2.w += hv.z * w4[kk].w;                                  \
      a3.x += hv.w * w4[kk].x; a3.y += hv.w * w4[kk].y;                                  \
      a3.z += hv.w * w4[kk].z; a3.w += hv.w * w4[kk].w;                                  \
    }                                                                                    \
    _Pragma("unroll")                                                                    \
    for (int off = 2; off < 64; off <<= 1) {                                             \
      a0.x += __shfl_xor(a0.x, off); a0.y += __shfl_xor(a0.y, off);                      \
      a0.z += __shfl_xor(a0.z, off); a0.w += __shfl_xor(a0.w, off);                      \
      a1.x += __shfl_xor(a1.x, off); a1.y += __shfl_xor(a1.y, off);                      \
      a1.z += __shfl_xor(a1.z, off); a1.w += __shfl_xor(a1.w, off);                      \
      a2.x += __shfl_xor(a2.x, off); a2.y += __shfl_xor(a2.y, off);                      \
      a2.z += __shfl_xor(a2.z, off); a2.w += __shfl_xor(a2.w, off);                      \
      a3.x += __shfl_xor(a3.x, off); a3.y += __shfl_xor(a3.y, off);                      \
      a3.z += __shfl_xor(a3.z, off); a3.w += __shfl_xor(a3.w, off);                      \
    }                                                                                    \
    if (lane < 32) {                                                                     \
      float4 rw = (b_w == 0) ? a0 : (b_w == 1) ? a1 : (b_w == 2) ? a2 : a3;              \
      float val = (ji_w == 0) ? rw.x : (ji_w == 1) ? rw.y : (ji_w == 2) ? rw.z : rw.w;   \
      g_l[GIDX][b_w][jwr] = val + (GV);                                                  \
    }                                                                                    \
  }

// ---------------- persistent decoder: 256 blocks x 512 threads, 1 block/CU ----------------
// block (pr, ug): pair pr handles batch-groups A = [4pr,4pr+4) and B = [32+4pr, 32+4pr+4),
// u-slice [16ug, 16ug+16). Ping-pong schedule hides LLC barrier latency behind GEMMs.
__global__ __launch_bounds__(512, 1) void decoder_persist(
    const float* __restrict__ Wr,        // [512][2048]
    const float* __restrict__ Wgen,      // [1280][512]
    const float* __restrict__ bgen,      // [512]
    const float* __restrict__ enc_h,     // [64][512]
    const float* __restrict__ enc_c,     // [64][512]
    const float* __restrict__ embW,      // [512][2048]
    const float* __restrict__ xg0,       // [2048][2048]
    const float* __restrict__ enc_part,  // [2048][512]
    const float* __restrict__ dec0,      // [2048][512]
    const float* __restrict__ decW,      // [512][512]
    float* __restrict__ hbT,             // [8 pair][2 par][2 grp][512 k][4 b]
    int*   __restrict__ idxbuf,          // [2][2048]
    unsigned* __restrict__ flags,        // [8 pair][2 grp][32 ug][16]
    float* __restrict__ out)
{
  __shared__ __align__(16) float hredA[2048];
  __shared__ __align__(16) float hredB[2048];
  __shared__ __align__(16) float Wgenl[8192];     // [k][ul] 32 KB
  __shared__ float g_l[2][4][68];
  __shared__ float hW_l[128];                     // [g][b*16+ul]
  __shared__ float redl[512];
  __shared__ int   idx_l[8][32];
  __shared__ float bgen_l[16];

  const int tid = threadIdx.x;
  const int bid = blockIdx.x;
  const int pr = bid >> 5, ug = bid & 31;
  const int bA0 = pr * 4, bB0 = 32 + pr * 4;
  const int u0 = ug * 16;
  const int w = tid >> 6, lane = tid & 63;
  const int ks = lane >> 1, jsub = lane & 1;
  const int b_w = ks >> 2, ji_w = ks & 3;
  const int jloc = w * 8 + jsub * 4;
  const int gcol0 = (jloc >> 4) * Uz + u0 + (jloc & 15);
  const int jwr = jloc + ji_w;
  const int gcolw = gcol0 + ji_w;
  const int p_b = lane >> 4, p_ul = lane & 15;

  float* out_dec = out;
  float* out_pg  = out + (size_t)NITER * Bz * Tz * Uz;
  float* out_hs  = out + 2 * (size_t)NITER * Bz * Tz * Uz;
  float* out_cs  = out_hs + (size_t)NITER * Bz * Uz;

  unsigned* flA = flags + (pr * 2 + 0) * 512;
  unsigned* flB = flags + (pr * 2 + 1) * 512;
  float* hbTp = hbT + pr * 8192;                  // [par][g][512][4]

  // ---- one-time staging ----
  float4 w4[16];
#pragma unroll
  for (int kk = 0; kk < 16; ++kk)
    w4[kk] = *(const float4*)&Wr[(size_t)(kk * 32 + ks) * G4 + gcol0];
  for (int q = 0; q < 16; ++q) {
    int e = q * 512 + tid, k = e >> 4, ul = e & 15;
    Wgenl[k * 16 + ul] = Wgen[(size_t)(512 + k) * Uz + u0 + ul];
  }
  if (tid < 16) bgen_l[tid] = bgen[u0 + tid];
  {
    int k = tid;
#pragma unroll
    for (int b = 0; b < 4; ++b) {
      hredA[k * 4 + b] = enc_h[(size_t)(bA0 + b) * Uz + k];
      hredB[k * 4 + b] = enc_h[(size_t)(bB0 + b) * Uz + k];
    }
  }
  float c_reg = 0.f;
  if (w == 0) c_reg = enc_c[(size_t)(bA0 + p_b) * Uz + u0 + p_ul];
  if (w == 1) c_reg = enc_c[(size_t)(bB0 + p_b) * Uz + u0 + p_ul];
  __syncthreads();

#pragma unroll 1
  for (int s = 0; s < NITER; ++s) {
    const int* idxp = idxbuf + ((s + 1) & 1) * 2048;
    int*       idxq = idxbuf + (s & 1) * 2048;
    const unsigned base = 33u * s;

    // ---- iter boundary: idx staging, hW, hs/cs, p_gen ----
    if (s > 0) {
      if (w == 1 && lane < 32) poll32(flA, base);   // all blocks' argmax(s-1) done
      __syncthreads();
      if (tid < 256) {
        int pb = tid >> 5, t = tid & 31;
        int batch = (pb < 4) ? bA0 + pb : bB0 + (pb - 4);
        idx_l[pb][t] = AT_LOADI(&idxp[batch * Tz + t]);
      }
    }
    {  // hW = h_pre @ Wgen[512:1024]: partials over 4 k-quarters
      int g = tid >> 8, r6 = tid & 255, kq = r6 >> 6, l6 = r6 & 63;
      int b = l6 >> 4, ul = l6 & 15;
      const float* hr = g ? hredB : hredA;
      float a = 0.f;
#pragma unroll 8
      for (int k = kq * 128; k < kq * 128 + 128; ++k)
        a += hr[k * 4 + b] * Wgenl[k * 16 + ul];
      redl[tid] = a;
    }
    __syncthreads();
    if (tid < 128) {
      int g = tid >> 6, l6 = tid & 63;
      hW_l[tid] = (redl[g * 256 + l6] + redl[g * 256 + 64 + l6]) +
                  (redl[g * 256 + 128 + l6] + redl[g * 256 + 192 + l6]);
    }
    if (w < 2) {  // scan outputs: pre-update h, c
      int batch = (w == 0 ? bA0 : bB0) + p_b;
      const float* hr = w ? hredB : hredA;
      out_hs[((size_t)s * Bz + batch) * Uz + u0 + p_ul] = hr[(u0 + p_ul) * 4 + p_b];
      out_cs[((size_t)s * Bz + batch) * Uz + u0 + p_ul] = c_reg;
    }
    __syncthreads();
    // p_gen (reads idx(s-1) via idx_l; hW_l block-local)
#pragma unroll 1
    for (int i = 0; i < 8; ++i) {
      int o = i * 512 + tid;
      int ul = o & 15, t = (o >> 4) & 31, pb = o >> 9;
      int batch = (pb < 4) ? bA0 + pb : bB0 + (pb - 4);
      size_t r = (size_t)batch * Tz + t;
      float dv = (s == 0) ? dec0[r * Uz + u0 + ul]
                          : decW[(size_t)idx_l[pb][t] * Uz + u0 + ul];
      float v = enc_part[r * Uz + u0 + ul] + hW_l[(pb >> 2) * 64 + (pb & 3) * 16 + ul]
              + dv + bgen_l[ul];
      out_pg[(((size_t)s * Bz + batch) * Tz + t) * Uz + u0 + ul] = sigf(v);
    }

    // ---- 32 LSTM steps, ping-pong A/B ----
#pragma unroll 1
    for (int t = 0; t < Tz; ++t) {
      const int gt = s * Tz + t;
      // ===== P1: GEMM A (wave1 first confirms h_B(t) flags) =====
      float gvA = 0.f;
      if (lane < 32) {
        int r = (bA0 + b_w) * Tz + t;
        gvA = (s == 0) ? xg0[(size_t)r * G4 + gcolw]
                       : embW[(size_t)idx_l[b_w][t] * G4 + gcolw];
      }
      if (w == 1 && lane < 32) poll32(flB, base + t);
      DO_GEMM(hredA, 0, gvA);
      __syncthreads();
      // ===== P2: pointwise A (wave0) | stage hredB(t) (waves 2-5) =====
      float gvB = 0.f;
      if (lane < 32) {
        int r = (bB0 + b_w) * Tz + t;
        gvB = (s == 0) ? xg0[(size_t)r * G4 + gcolw]
                       : embW[(size_t)idx_l[4 + b_w][t] * G4 + gcolw];
      }
      if (w == 0) {
        float gi = g_l[0][p_b][p_ul],      gf = g_l[0][p_b][16 + p_ul];
        float gc = g_l[0][p_b][32 + p_ul], go = g_l[0][p_b][48 + p_ul];
        c_reg = sigf(gf) * c_reg + sigf(gi) * tanhf(gc);
        float hn = sigf(go) * tanhf(c_reg);
        int parw = (gt + 1) & 1;
        AT_STORE(&hbTp[(parw * 2 + 0) * 2048 + (u0 + p_ul) * 4 + p_b], hn);
        AT_STORE(&out_dec[(((size_t)s * Bz + bA0 + p_b) * Tz + t) * Uz + u0 + p_ul], hn);
        asm volatile("s_waitcnt vmcnt(0)" ::: "memory");
        if (lane == 0) AT_STORE(&flA[ug * 16], base + t + 1);
      } else if (w >= 2 && w < 6 && gt > 0) {
        int st = tid - 128;
        const ull* src = (const ull*)&hbTp[((gt & 1) * 2 + 1) * 2048];
        ull* dst = (ull*)hredB;
#pragma unroll
        for (int q = 0; q < 4; ++q) dst[st * 4 + q] = AT_LOAD64(&src[st * 4 + q]);
      }
      __syncthreads();
      // ===== P3: GEMM B (wave6 first confirms h_A(t+1) flags) =====
      if (w == 6 && lane < 32) poll32(flA, base + t + 1);
      DO_GEMM(hredB, 1, gvB);
      __syncthreads();
      // ===== P4: pointwise B (wave1) | stage hredA(t+1) (waves 2-5) =====
      if (w == 1) {
        float gi = g_l[1][p_b][p_ul],      gf = g_l[1][p_b][16 + p_ul];
        float gc = g_l[1][p_b][32 + p_ul], go = g_l[1][p_b][48 + p_ul];
        c_reg = sigf(gf) * c_reg + sigf(gi) * tanhf(gc);
        float hn = sigf(go) * tanhf(c_reg);
        int parw = (gt + 1) & 1;
        AT_STORE(&hbTp[(parw * 2 + 1) * 2048 + (u0 + p_ul) * 4 + p_b], hn);
        AT_STORE(&out_dec[(((size_t)s * Bz + bB0 + p_b) * Tz + t) * Uz + u0 + p_ul], hn);
        asm volatile("s_waitcnt vmcnt(0)" ::: "memory");
        if (lane == 0) AT_STORE(&flB[ug * 16], base + t + 1);
      } else if (w >= 2 && w < 6) {
        int st = tid - 128;
        const ull* src = (const ull*)&hbTp[(((gt + 1) & 1) * 2 + 0) * 2048];
        ull* dst = (ull*)hredA;
#pragma unroll
        for (int q = 0; q < 4; ++q) dst[st * 4 + q] = AT_LOAD64(&src[st * 4 + q]);
      }
      __syncthreads();
    }

    // ---- argmax(s) -> idx slot s (skip on last iter) ----
    if (s < NITER - 1) {
      if (w == 1 && lane < 32) poll32(flB, base + 32);  // all blocks' t=31 B writes
      __syncthreads();
      {
        int R = ug * 8 + w;
        int pb = R >> 5, t = R & 31;
        int batch = (pb < 4) ? bA0 + pb : bB0 + (pb - 4);
        const float* row = &out_dec[(((size_t)s * Bz + batch) * Tz + t) * Uz];
        float bv = -3.4e38f; int bi = 0;
#pragma unroll
        for (int q = 0; q < 8; ++q) {
          int u = lane + q * 64;
          float v = AT_LOADF(&row[u]);
          if (v > bv) { bv = v; bi = u; }
        }
#pragma unroll
        for (int off = 1; off < 64; off <<= 1) {
          float ov = __shfl_xor(bv, off);
          int   oi = __shfl_xor(bi, off);
          if (ov > bv || (ov == bv && oi < bi)) { bv = ov; bi = oi; }
        }
        if (lane == 0) AT_STORE(&idxq[batch * Tz + t], bi);
      }
      asm volatile("s_waitcnt vmcnt(0)" ::: "memory");
      __syncthreads();
      if (tid == 0) {
        AT_STORE(&flA[ug * 16], base + 33);
        AT_STORE(&flB[ug * 16], base + 33);
      }
    }
  }
}

extern "C" void kernel_launch(void* const* d_in, const int* in_sizes, int n_in,
                              void* d_out, int out_size, void* d_ws, size_t ws_size,
                              hipStream_t stream) {
  const int*   target = (const int*)d_in[1];
  const float* enc    = (const float*)d_in[2];
  const float* enc_h  = (const float*)d_in[3];
  const float* enc_cp = (const float*)d_in[4];
  const float* emb    = (const float*)d_in[5];
  const float* Wk     = (const float*)d_in[6];
  const float* Wr     = (const float*)d_in[7];
  const float* bb     = (const float*)d_in[8];
  const float* Wgen   = (const float*)d_in[9];
  const float* bgen   = (const float*)d_in[10];
  float* out = (float*)d_out;

  float* ws = (float*)d_ws;
  float* hbT      = ws;                         // 8*2*2*512*4   = 65536
  float* embW     = ws + 65536;                 // 512*2048      = 1048576
  float* xg0      = ws + 1114112;               // 2048*2048     = 4194304
  float* enc_part = ws + 5308416;               // 2048*512      = 1048576
  float* dec0     = ws + 6356992;               // 2048*512      = 1048576
  float* decW     = ws + 7405568;               // 512*512       = 262144
  int*   idxbuf   = (int*)(ws + 7667712);       // 2*2048
  unsigned* flags = (unsigned*)(ws + 7671808);  // 8*2*512 = 8192

  init_kernel<<<16, 512, 0, stream>>>(flags);
  // embW = emb[0:512] @ Wk + b           M=512  N=2048 K=256
  gemm_f32<<<dim3(32, 8), 256, 0, stream>>>(emb, nullptr, 256, Wk, 2048, bb, embW, 2048, 256);
  // xg0 = emb[target] @ Wk + b           M=2048 N=2048 K=256
  gemm_f32<<<dim3(32, 32), 256, 0, stream>>>(emb, target, 256, Wk, 2048, bb, xg0, 2048, 256);
  // enc_part = enc @ Wgen[0:512]         M=2048 N=512  K=512
  gemm_f32<<<dim3(8, 32), 256, 0, stream>>>(enc, nullptr, 512, Wgen, 512, nullptr, enc_part, 512, 512);
  // dec0 = emb[target] @ Wgen[1024:1280] M=2048 N=512  K=256
  gemm_f32<<<dim3(8, 32), 256, 0, stream>>>(emb, target, 256, Wgen + 1024 * 512, 512, nullptr, dec0, 512, 256);
  // decW = emb[0:512] @ Wgen[1024:1280]  M=512  N=512  K=256
  gemm_f32<<<dim3(8, 8), 256, 0, stream>>>(emb, nullptr, 256, Wgen + 1024 * 512, 512, nullptr, decW, 512, 256);

  decoder_persist<<<256, 512, 0, stream>>>(Wr, Wgen, bgen, enc_h, enc_cp, embW, xg0,
      enc_part, dec0, decW, hbT, idxbuf, flags, out);
}

// Round 6
// 5793.972 us; speedup vs baseline: 1.3546x; 1.3546x over previous
//
#include <hip/hip_runtime.h>
#include <math.h>

#define Bz 64
#define Tz 32
#define Uz 512
#define NITER 31
#define G4 2048

typedef unsigned long long ull;

__device__ __forceinline__ float sigf(float x) { return 1.f / (1.f + expf(-x)); }

#define AT_LOADF(p)   __hip_atomic_load((p), __ATOMIC_RELAXED, __HIP_MEMORY_SCOPE_AGENT)
#define AT_LOADI(p)   __hip_atomic_load((p), __ATOMIC_RELAXED, __HIP_MEMORY_SCOPE_AGENT)
#define AT_LOAD64(p)  __hip_atomic_load((p), __ATOMIC_RELAXED, __HIP_MEMORY_SCOPE_AGENT)
#define AT_STORE(p,v) __hip_atomic_store((p), (v), __ATOMIC_RELAXED, __HIP_MEMORY_SCOPE_AGENT)

// poll 32 per-block flag lines; call with 32 active lanes (lane<32 of one wave)
__device__ __forceinline__ void poll32(unsigned* fl, unsigned target) {
  int sl = threadIdx.x & 63;
  unsigned v;
  do {
    v = __hip_atomic_fetch_add(&fl[sl * 16], 0u, __ATOMIC_RELAXED, __HIP_MEMORY_SCOPE_AGENT);
  } while (__any((int)(v < target)));
}

// ---------------- generic f32 GEMM: C[M,N] = A[rows][K] @ B[K,N] (+bias) ----------------
__global__ __launch_bounds__(256) void gemm_f32(
    const float* __restrict__ A, const int* __restrict__ Arows, int lda,
    const float* __restrict__ Bm, int ldb, const float* __restrict__ bias,
    float* __restrict__ C, int N, int K)
{
  __shared__ __align__(16) float As[16][68];
  __shared__ __align__(16) float Bs[16][68];
  const int tid = threadIdx.x;
  const int bm = blockIdx.y, bn = blockIdx.x;
  const int tx = tid & 15, ty = tid >> 4;
  float acc[4][4] = {{0.f}};
  const int sm = tid >> 2, sk = (tid & 3) * 4;
  const int arow = Arows ? Arows[bm * 64 + sm] : (bm * 64 + sm);
  const float* Ap = A + (size_t)arow * lda + sk;
  const int bk = tid >> 4, bn4 = (tid & 15) * 4;
  const float* Bp = Bm + (size_t)bk * ldb + bn * 64 + bn4;
  for (int kk = 0; kk < K; kk += 16) {
    float4 av = *(const float4*)(Ap + kk);
    float4 bv = *(const float4*)(Bp + (size_t)kk * ldb);
    As[sk + 0][sm] = av.x; As[sk + 1][sm] = av.y;
    As[sk + 2][sm] = av.z; As[sk + 3][sm] = av.w;
    *(float4*)&Bs[bk][bn4] = bv;
    __syncthreads();
#pragma unroll
    for (int kt = 0; kt < 16; ++kt) {
      float4 a = *(const float4*)&As[kt][ty * 4];
      float4 b = *(const float4*)&Bs[kt][tx * 4];
      acc[0][0] += a.x * b.x; acc[0][1] += a.x * b.y; acc[0][2] += a.x * b.z; acc[0][3] += a.x * b.w;
      acc[1][0] += a.y * b.x; acc[1][1] += a.y * b.y; acc[1][2] += a.y * b.z; acc[1][3] += a.y * b.w;
      acc[2][0] += a.z * b.x; acc[2][1] += a.z * b.y; acc[2][2] += a.z * b.z; acc[2][3] += a.z * b.w;
      acc[3][0] += a.w * b.x; acc[3][1] += a.w * b.y; acc[3][2] += a.w * b.z; acc[3][3] += a.w * b.w;
    }
    __syncthreads();
  }
  const int cm = bm * 64 + ty * 4, cn = bn * 64 + tx * 4;
  float bc0 = bias ? bias[cn + 0] : 0.f;
  float bc1 = bias ? bias[cn + 1] : 0.f;
  float bc2 = bias ? bias[cn + 2] : 0.f;
  float bc3 = bias ? bias[cn + 3] : 0.f;
#pragma unroll
  for (int i = 0; i < 4; ++i) {
    float4 o;
    o.x = acc[i][0] + bc0; o.y = acc[i][1] + bc1;
    o.z = acc[i][2] + bc2; o.w = acc[i][3] + bc3;
    *(float4*)&C[(size_t)(cm + i) * N + cn] = o;
  }
}

__global__ void init_kernel(unsigned* __restrict__ flags) {
  int i = blockIdx.x * blockDim.x + threadIdx.x;
  if (i < 8192) flags[i] = 0u;
}

// GEMM: h from LDS (contiguous b128, pair-broadcast), W in regs (w4[16]),
// halving select+shuffle reduce: 16 shuffles/thread. Final output per lane
// (ks<16): b = 2*(ks&1)+((ks>>1)&1), ji = 2*((ks>>2)&1)+((ks>>3)&1).
#define DO_GEMM(HRED, GIDX, GV)                                                          \
  {                                                                                      \
    float4 a0 = {0,0,0,0}, a1 = {0,0,0,0}, a2 = {0,0,0,0}, a3 = {0,0,0,0};               \
    _Pragma("unroll")                                                                    \
    for (int kk = 0; kk < 16; ++kk) {                                                    \
      float4 hv = *(const float4*)&HRED[(kk * 32 + ks) * 4];                             \
      a0.x += hv.x * w4[kk].x; a0.y += hv.x * w4[kk].y;                                  \
      a0.z += hv.x * w4[kk].z; a0.w += hv.x * w4[kk].w;                                  \
      a1.x += hv.y * w4[kk].x; a1.y += hv.y * w4[kk].y;                                  \
      a1.z += hv.y * w4[kk].z; a1.w += hv.y * w4[kk].w;                                  \
      a2.x += hv.z * w4[kk].x; a2.y += hv.z * w4[kk].y;                                  \
      a2.z += hv.z * w4[kk].z; a2.w += hv.z * w4[kk].w;                                  \
      a3.x += hv.w * w4[kk].x; a3.y += hv.w * w4[kk].y;                                  \
      a3.z += hv.w * w4[kk].z; a3.w += hv.w * w4[kk].w;                                  \
    }                                                                                    \
    bool c1 = ks & 1, c2 = ks & 2, c3 = ks & 4, c4 = ks & 8;                             \
    float4 k0 = c1 ? a2 : a0, k1 = c1 ? a3 : a1;                                         \
    float4 s0 = c1 ? a0 : a2, s1 = c1 ? a1 : a3;                                         \
    k0.x += __shfl_xor(s0.x, 2); k0.y += __shfl_xor(s0.y, 2);                            \
    k0.z += __shfl_xor(s0.z, 2); k0.w += __shfl_xor(s0.w, 2);                            \
    k1.x += __shfl_xor(s1.x, 2); k1.y += __shfl_xor(s1.y, 2);                            \
    k1.z += __shfl_xor(s1.z, 2); k1.w += __shfl_xor(s1.w, 2);                            \
    float4 m0 = c2 ? k1 : k0, n0 = c2 ? k0 : k1;                                         \
    m0.x += __shfl_xor(n0.x, 4); m0.y += __shfl_xor(n0.y, 4);                            \
    m0.z += __shfl_xor(n0.z, 4); m0.w += __shfl_xor(n0.w, 4);                            \
    float q0 = c3 ? m0.z : m0.x, q1 = c3 ? m0.w : m0.y;                                  \
    float r0 = c3 ? m0.x : m0.z, r1 = c3 ? m0.y : m0.w;                                  \
    q0 += __shfl_xor(r0, 8); q1 += __shfl_xor(r1, 8);                                    \
    float u_ = c4 ? q1 : q0, v_ = c4 ? q0 : q1;                                          \
    u_ += __shfl_xor(v_, 16);                                                            \
    u_ += __shfl_xor(u_, 32);                                                            \
    if (lane < 32) g_l[GIDX][b_f][j_f] = u_ + (GV);                                      \
  }

// ---------------- persistent decoder: 256 blocks x 512 threads, 1 block/CU ----------------
// block (pr, ug): pair pr handles batch-groups A = [4pr,4pr+4) and B = [32+4pr,+4),
// u-slice [16ug, +16). Ping-pong A/B; staging waves hide LLC latency under GEMMs.
__global__ __launch_bounds__(512, 1) void decoder_persist(
    const float* __restrict__ Wr,        // [512][2048]
    const float* __restrict__ Wgen,      // [1280][512]
    const float* __restrict__ bgen,      // [512]
    const float* __restrict__ enc_h,     // [64][512]
    const float* __restrict__ enc_c,     // [64][512]
    const float* __restrict__ embW,      // [512][2048]
    const float* __restrict__ xg0,       // [2048][2048]
    const float* __restrict__ enc_part,  // [2048][512]
    const float* __restrict__ dec0,      // [2048][512]
    const float* __restrict__ decW,      // [512][512]
    float* __restrict__ hbT,             // [8 pair][2 par][2 grp][512 k][4 b]
    int*   __restrict__ idxbuf,          // [2][2048]
    unsigned* __restrict__ flags,        // [8 pair][2 grp][32 ug][16]
    float* __restrict__ out)
{
  __shared__ __align__(16) float hredA[2048];
  __shared__ __align__(16) float hredB[2048];
  __shared__ __align__(16) float Wgenl[8192];     // [k][ul] 32 KB
  __shared__ float g_l[2][4][68];
  __shared__ float hW_l[128];                     // [g][b*16+ul]
  __shared__ float redl[512];
  __shared__ int   idx_l[8][32];
  __shared__ float bgen_l[16];

  const int tid = threadIdx.x;
  const int bid = blockIdx.x;
  const int pr = bid >> 5, ug = bid & 31;
  const int bA0 = pr * 4, bB0 = 32 + pr * 4;
  const int u0 = ug * 16;
  const int w = tid >> 6, lane = tid & 63;
  const int ks = lane >> 1, jsub = lane & 1;
  const int jloc = w * 8 + jsub * 4;              // base of this thread's 4 j's
  const int gcol0 = (jloc >> 4) * Uz + u0 + (jloc & 15);
  // final-output mapping after halving reduce (valid for lane<32, i.e. ks<16)
  const int b_f = 2 * (ks & 1) + ((ks >> 1) & 1);
  const int ji_f = 2 * ((ks >> 2) & 1) + ((ks >> 3) & 1);
  const int j_f = jloc + ji_f;
  const int gcol_f = (j_f >> 4) * Uz + u0 + (j_f & 15);
  const int p_b = lane >> 4, p_ul = lane & 15;

  float* out_dec = out;
  float* out_pg  = out + (size_t)NITER * Bz * Tz * Uz;
  float* out_hs  = out + 2 * (size_t)NITER * Bz * Tz * Uz;
  float* out_cs  = out_hs + (size_t)NITER * Bz * Uz;

  unsigned* flA = flags + (pr * 2 + 0) * 512;
  unsigned* flB = flags + (pr * 2 + 1) * 512;
  float* hbTp = hbT + pr * 8192;                  // [par][g][512][4]

  // ---- one-time staging ----
  float4 w4[16];
#pragma unroll
  for (int kk = 0; kk < 16; ++kk)
    w4[kk] = *(const float4*)&Wr[(size_t)(kk * 32 + ks) * G4 + gcol0];
  for (int q = 0; q < 16; ++q) {
    int e = q * 512 + tid, k = e >> 4, ul = e & 15;
    Wgenl[k * 16 + ul] = Wgen[(size_t)(512 + k) * Uz + u0 + ul];
  }
  if (tid < 16) bgen_l[tid] = bgen[u0 + tid];
  {
    int k = tid;
#pragma unroll
    for (int b = 0; b < 4; ++b) {
      hredA[k * 4 + b] = enc_h[(size_t)(bA0 + b) * Uz + k];
      hredB[k * 4 + b] = enc_h[(size_t)(bB0 + b) * Uz + k];
    }
  }
  float c_reg = 0.f;
  if (w == 0) c_reg = enc_c[(size_t)(bA0 + p_b) * Uz + u0 + p_ul];
  if (w == 1) c_reg = enc_c[(size_t)(bB0 + p_b) * Uz + u0 + p_ul];
  __syncthreads();

#pragma unroll 1
  for (int s = 0; s < NITER; ++s) {
    const int* idxp = idxbuf + ((s + 1) & 1) * 2048;
    int*       idxq = idxbuf + (s & 1) * 2048;
    const unsigned base = 33u * s;

    // ---- iter boundary ----
    if (s > 0) {
      if (w == 1 && lane < 32) poll32(flA, base);   // all blocks' argmax(s-1) done
      __syncthreads();
      if (tid < 128) {                              // idx_l: 8 pb x 32 t
        int pb = tid >> 4, t2 = (tid & 15) * 2;
        int batch = (pb < 4) ? bA0 + pb : bB0 + (pb - 4);
        idx_l[pb][t2]     = AT_LOADI(&idxp[batch * Tz + t2]);
        idx_l[pb][t2 + 1] = AT_LOADI(&idxp[batch * Tz + t2 + 1]);
      } else if (w >= 2 && w < 6) {                 // re-stage hredB fresh (h after t=31)
        int st = tid - 128;
        const ull* src = (const ull*)&hbTp[1 * 2048];   // parity(32s)=0 -> B slot 1
        ull* dst = (ull*)hredB;
#pragma unroll
        for (int q = 0; q < 4; ++q) dst[q * 256 + st] = AT_LOAD64(&src[q * 256 + st]);
      }
      __syncthreads();
    }
    {  // hW = h_pre @ Wgen[512:1024]: partials over 4 k-quarters
      int g = tid >> 8, r6 = tid & 255, kq = r6 >> 6, l6 = r6 & 63;
      int b = l6 >> 4, ul = l6 & 15;
      const float* hr = g ? hredB : hredA;
      float a = 0.f;
#pragma unroll 8
      for (int k = kq * 128; k < kq * 128 + 128; ++k)
        a += hr[k * 4 + b] * Wgenl[k * 16 + ul];
      redl[tid] = a;
    }
    __syncthreads();
    if (tid < 128) {
      int g = tid >> 6, l6 = tid & 63;
      hW_l[tid] = (redl[g * 256 + l6] + redl[g * 256 + 64 + l6]) +
                  (redl[g * 256 + 128 + l6] + redl[g * 256 + 192 + l6]);
    }
    if (w < 2) {  // scan outputs: pre-update h, c
      int batch = (w == 0 ? bA0 : bB0) + p_b;
      const float* hr = w ? hredB : hredA;
      out_hs[((size_t)s * Bz + batch) * Uz + u0 + p_ul] = hr[(u0 + p_ul) * 4 + p_b];
      out_cs[((size_t)s * Bz + batch) * Uz + u0 + p_ul] = c_reg;
    }
    __syncthreads();
    // p_gen (reads idx(s-1) via idx_l; hW_l block-local)
#pragma unroll 1
    for (int i = 0; i < 8; ++i) {
      int o = i * 512 + tid;
      int ul = o & 15, t = (o >> 4) & 31, pb = o >> 9;
      int batch = (pb < 4) ? bA0 + pb : bB0 + (pb - 4);
      size_t r = (size_t)batch * Tz + t;
      float dv = (s == 0) ? dec0[r * Uz + u0 + ul]
                          : decW[(size_t)idx_l[pb][t] * Uz + u0 + ul];
      float v = enc_part[r * Uz + u0 + ul] + hW_l[(pb >> 2) * 64 + (pb & 3) * 16 + ul]
              + dv + bgen_l[ul];
      out_pg[(((size_t)s * Bz + batch) * Tz + t) * Uz + u0 + ul] = sigf(v);
    }

    // ---- 32 LSTM steps, ping-pong A/B ----
#pragma unroll 1
    for (int t = 0; t < Tz; ++t) {
      const int gt = s * Tz + t;
      ull stg[16];
      // ===== P1: GEMM A; wave1 polls flB(t), prefetches h_B(t) to regs =====
      float gvA = 0.f, gvB = 0.f;
      if (lane < 32) {
        int rA = (bA0 + b_f) * Tz + t, rB = (bB0 + b_f) * Tz + t;
        if (s == 0) {
          gvA = xg0[(size_t)rA * G4 + gcol_f];
          gvB = xg0[(size_t)rB * G4 + gcol_f];
        } else {
          gvA = embW[(size_t)idx_l[b_f][t] * G4 + gcol_f];
          gvB = embW[(size_t)idx_l[4 + b_f][t] * G4 + gcol_f];
        }
      }
      if (w == 1 && gt > 0) {
        if (lane < 32) poll32(flB, base + t);
        const ull* src = (const ull*)&hbTp[((gt & 1) * 2 + 1) * 2048];
#pragma unroll
        for (int q = 0; q < 16; ++q) stg[q] = AT_LOAD64(&src[q * 64 + lane]);
      }
      DO_GEMM(hredA, 0, gvA);
      __syncthreads();
      // ===== P2: pointwise A (w0) | hredB LDS write (w1) =====
      if (w == 0) {
        float gi = g_l[0][p_b][p_ul],      gf = g_l[0][p_b][16 + p_ul];
        float gc = g_l[0][p_b][32 + p_ul], go = g_l[0][p_b][48 + p_ul];
        c_reg = sigf(gf) * c_reg + sigf(gi) * tanhf(gc);
        float hn = sigf(go) * tanhf(c_reg);
        int parw = (gt + 1) & 1;
        AT_STORE(&hbTp[(parw * 2 + 0) * 2048 + (u0 + p_ul) * 4 + p_b], hn);
        AT_STORE(&out_dec[(((size_t)s * Bz + bA0 + p_b) * Tz + t) * Uz + u0 + p_ul], hn);
        asm volatile("s_waitcnt vmcnt(0)" ::: "memory");
        if (lane == 0) AT_STORE(&flA[ug * 16], base + t + 1);
      } else if (w == 1 && gt > 0) {
        ull* dst = (ull*)hredB;
#pragma unroll
        for (int q = 0; q < 16; ++q) dst[q * 64 + lane] = stg[q];
      }
      __syncthreads();
      // ===== P3: GEMM B; wave6 polls flA(t+1), prefetches h_A(t+1) to regs =====
      if (w == 6) {
        if (lane < 32) poll32(flA, base + t + 1);
        const ull* src = (const ull*)&hbTp[(((gt + 1) & 1) * 2 + 0) * 2048];
#pragma unroll
        for (int q = 0; q < 16; ++q) stg[q] = AT_LOAD64(&src[q * 64 + lane]);
      }
      DO_GEMM(hredB, 1, gvB);
      __syncthreads();
      // ===== P4: pointwise B (w1) | hredA LDS write (w6) =====
      if (w == 1) {
        float gi = g_l[1][p_b][p_ul],      gf = g_l[1][p_b][16 + p_ul];
        float gc = g_l[1][p_b][32 + p_ul], go = g_l[1][p_b][48 + p_ul];
        c_reg = sigf(gf) * c_reg + sigf(gi) * tanhf(gc);
        float hn = sigf(go) * tanhf(c_reg);
        int parw = (gt + 1) & 1;
        AT_STORE(&hbTp[(parw * 2 + 1) * 2048 + (u0 + p_ul) * 4 + p_b], hn);
        AT_STORE(&out_dec[(((size_t)s * Bz + bB0 + p_b) * Tz + t) * Uz + u0 + p_ul], hn);
        asm volatile("s_waitcnt vmcnt(0)" ::: "memory");
        if (lane == 0) AT_STORE(&flB[ug * 16], base + t + 1);
      } else if (w == 6) {
        ull* dst = (ull*)hredA;
#pragma unroll
        for (int q = 0; q < 16; ++q) dst[q * 64 + lane] = stg[q];
      }
      __syncthreads();
    }

    // ---- argmax(s) -> idx slot s (skip on last iter) ----
    if (s < NITER - 1) {
      if (w == 1 && lane < 32) poll32(flB, base + 32);
      __syncthreads();
      {
        int R = ug * 8 + w;
        int pb = R >> 5, t = R & 31;
        int batch = (pb < 4) ? bA0 + pb : bB0 + (pb - 4);
        const float* row = &out_dec[(((size_t)s * Bz + batch) * Tz + t) * Uz];
        float bv = -3.4e38f; int bi = 0;
#pragma unroll
        for (int q = 0; q < 8; ++q) {
          int u = lane + q * 64;
          float v = AT_LOADF(&row[u]);
          if (v > bv) { bv = v; bi = u; }
        }
#pragma unroll
        for (int off = 1; off < 64; off <<= 1) {
          float ov = __shfl_xor(bv, off);
          int   oi = __shfl_xor(bi, off);
          if (ov > bv || (ov == bv && oi < bi)) { bv = ov; bi = oi; }
        }
        if (lane == 0) AT_STORE(&idxq[batch * Tz + t], bi);
      }
      asm volatile("s_waitcnt vmcnt(0)" ::: "memory");
      __syncthreads();
      if (tid == 0) {
        AT_STORE(&flA[ug * 16], base + 33);
        AT_STORE(&flB[ug * 16], base + 33);
      }
    }
  }
}

extern "C" void kernel_launch(void* const* d_in, const int* in_sizes, int n_in,
                              void* d_out, int out_size, void* d_ws, size_t ws_size,
                              hipStream_t stream) {
  const int*   target = (const int*)d_in[1];
  const float* enc    = (const float*)d_in[2];
  const float* enc_h  = (const float*)d_in[3];
  const float* enc_cp = (const float*)d_in[4];
  const float* emb    = (const float*)d_in[5];
  const float* Wk     = (const float*)d_in[6];
  const float* Wr     = (const float*)d_in[7];
  const float* bb     = (const float*)d_in[8];
  const float* Wgen   = (const float*)d_in[9];
  const float* bgen   = (const float*)d_in[10];
  float* out = (float*)d_out;

  float* ws = (float*)d_ws;
  float* hbT      = ws;                         // 8*2*2*512*4   = 65536
  float* embW     = ws + 65536;                 // 512*2048      = 1048576
  float* xg0      = ws + 1114112;               // 2048*2048     = 4194304
  float* enc_part = ws + 5308416;               // 2048*512      = 1048576
  float* dec0     = ws + 6356992;               // 2048*512      = 1048576
  float* decW     = ws + 7405568;               // 512*512       = 262144
  int*   idxbuf   = (int*)(ws + 7667712);       // 2*2048
  unsigned* flags = (unsigned*)(ws + 7671808);  // 8*2*512 = 8192

  init_kernel<<<16, 512, 0, stream>>>(flags);
  // embW = emb[0:512] @ Wk + b           M=512  N=2048 K=256
  gemm_f32<<<dim3(32, 8), 256, 0, stream>>>(emb, nullptr, 256, Wk, 2048, bb, embW, 2048, 256);
  // xg0 = emb[target] @ Wk + b           M=2048 N=2048 K=256
  gemm_f32<<<dim3(32, 32), 256, 0, stream>>>(emb, target, 256, Wk, 2048, bb, xg0, 2048, 256);
  // enc_part = enc @ Wgen[0:512]         M=2048 N=512  K=512
  gemm_f32<<<dim3(8, 32), 256, 0, stream>>>(enc, nullptr, 512, Wgen, 512, nullptr, enc_part, 512, 512);
  // dec0 = emb[target] @ Wgen[1024:1280] M=2048 N=512  K=256
  gemm_f32<<<dim3(8, 32), 256, 0, stream>>>(emb, target, 256, Wgen + 1024 * 512, 512, nullptr, dec0, 512, 256);
  // decW = emb[0:512] @ Wgen[1024:1280]  M=512  N=512  K=256
  gemm_f32<<<dim3(8, 8), 256, 0, stream>>>(emb, nullptr, 256, Wgen + 1024 * 512, 512, nullptr, decW, 512, 256);

  decoder_persist<<<256, 512, 0, stream>>>(Wr, Wgen, bgen, enc_h, enc_cp, embW, xg0,
      enc_part, dec0, decW, hbT, idxbuf, flags, out);
}